// Round 11
// baseline (567.757 us; speedup 1.0000x reference)
//
#include <hip/hip_runtime.h>
#include <hip/hip_bf16.h>

#define MM 131072

typedef __attribute__((ext_vector_type(8))) short short8;
typedef __attribute__((ext_vector_type(4))) float f32x4;

#define GLP(p) (const __attribute__((address_space(1))) void*)(p)
#define LDSP(p) (__attribute__((address_space(3))) void*)(p)

static __device__ __forceinline__ unsigned short f2bf(float f) {
    union { float f; unsigned int u; } v; v.f = f;
    unsigned int r = v.u + 0x7FFF + ((v.u >> 16) & 1);  // RNE
    return (unsigned short)(r >> 16);
}
static __device__ __forceinline__ float bf2f(unsigned short h) {
    union { float f; unsigned int u; } v; v.u = ((unsigned int)h) << 16;
    return v.f;
}

// ---------------------------------------------------------------------------
// fused fp32 -> bf16 conversion for x and u; also writes x into y cols 0..63
// ---------------------------------------------------------------------------
__global__ __launch_bounds__(256) void conv2_bf16(
    const float* __restrict__ x, const float* __restrict__ u,
    __hip_bfloat16* __restrict__ xb, __hip_bfloat16* __restrict__ ub,
    float* __restrict__ y)
{
    int i = blockIdx.x * 256 + threadIdx.x;
    const float* s; __hip_bfloat16* d; int j; bool isx;
    if (i < 2097152) { s = x; d = xb; j = i; isx = true; }
    else             { s = u; d = ub; j = i - 2097152; isx = false; }
    const float4 v = ((const float4*)s)[j];
    union { unsigned short h[4]; uint2 u2; } p;
    p.h[0] = f2bf(v.x); p.h[1] = f2bf(v.y);
    p.h[2] = f2bf(v.z); p.h[3] = f2bf(v.w);
    ((uint2*)d)[j] = p.u2;
    if (isx) {
        const int r = j >> 4, q = j & 15;
        ((float4*)(y + (size_t)r * 256))[q] = v;
    }
}

// fused W (K x N, f32) -> WT (N x K, bf16) for all 6 weights
__global__ __launch_bounds__(256) void wtrans_all(
    const float* __restrict__ W0, const float* __restrict__ W1,
    const float* __restrict__ W2, const float* __restrict__ W3,
    const float* __restrict__ W4, const float* __restrict__ W5,
    __hip_bfloat16* __restrict__ T0, __hip_bfloat16* __restrict__ T1,
    __hip_bfloat16* __restrict__ T2, __hip_bfloat16* __restrict__ T3,
    __hip_bfloat16* __restrict__ T4, __hip_bfloat16* __restrict__ T5)
{
    const int b = blockIdx.x;
    const float* W; __hip_bfloat16* T; int K, N, i0;
    if      (b < 64)  { W = W0; T = T0; K = 64;  N = 256; i0 = b; }
    else if (b < 320) { W = W1; T = T1; K = 256; N = 256; i0 = b - 64; }
    else if (b < 512) { W = W2; T = T2; K = 256; N = 192; i0 = b - 320; }
    else if (b < 576) { W = W3; T = T3; K = 64;  N = 256; i0 = b - 512; }
    else if (b < 768) { W = W4; T = T4; K = 256; N = 192; i0 = b - 576; }
    else              { W = W5; T = T5; K = 256; N = 256; i0 = b - 768; }
    const int i = i0 * 256 + threadIdx.x;
    if (i < K * N) {
        const int n = i / K, k = i - n * K;
        T[i] = __float2bfloat16(W[(size_t)k * N + n]);
    }
}

// ---------------------------------------------------------------------------
// Batched fp32 256x256x256 GEMMs for W-power products (up to 5 per launch).
// ---------------------------------------------------------------------------
struct G5 { const float* a[5]; const float* b[5]; float* c[5]; };

__global__ __launch_bounds__(256) void wgemm(G5 P)
{
    __shared__ __align__(16) float As[16][68];
    __shared__ __align__(16) float Ws[16][64];

    const int e  = blockIdx.x >> 4;
    const int tl = blockIdx.x & 15;
    const float* A = P.a[e];
    const float* W = P.b[e];
    float*       C = P.c[e];
    const int row0 = (tl >> 2) * 64;
    const int col0 = (tl & 3) * 64;

    const int tx = threadIdx.x & 15;
    const int ty = threadIdx.x >> 4;

    float acc[4][4] = {};

    for (int k0 = 0; k0 < 256; k0 += 16) {
        {
            const int kk = threadIdx.x & 15;
            const int r  = threadIdx.x >> 4;
            #pragma unroll
            for (int rr = 0; rr < 4; ++rr)
                As[kk][r + rr * 16] = A[(size_t)(row0 + r + rr * 16) * 256 + k0 + kk];
        }
        {
            const int n  = threadIdx.x & 63;
            const int kz = threadIdx.x >> 6;
            #pragma unroll
            for (int kq = 0; kq < 4; ++kq) {
                const int kk = kz + kq * 4;
                Ws[kk][n] = W[(size_t)(k0 + kk) * 256 + col0 + n];
            }
        }
        __syncthreads();
        #pragma unroll
        for (int kk = 0; kk < 16; ++kk) {
            const float4 a4 = *(const float4*)&As[kk][ty * 4];
            const float4 w4 = *(const float4*)&Ws[kk][tx * 4];
            const float av[4] = {a4.x, a4.y, a4.z, a4.w};
            const float wv[4] = {w4.x, w4.y, w4.z, w4.w};
            #pragma unroll
            for (int i = 0; i < 4; ++i)
                #pragma unroll
                for (int j = 0; j < 4; ++j)
                    acc[i][j] += av[i] * wv[j];
        }
        __syncthreads();
    }

    #pragma unroll
    for (int i = 0; i < 4; ++i)
        #pragma unroll
        for (int j = 0; j < 4; ++j)
            C[(size_t)(row0 + ty * 4 + i) * 256 + col0 + tx * 4 + j] = acc[i][j];
}

// build WBT8[n][j*256+k] = bf16( (WB W^j)[k][n] ), 256 x 2048 bf16
struct P8 { const float* m[8]; };
__global__ __launch_bounds__(256) void bigbt8(P8 p, __hip_bfloat16* __restrict__ T8)
{
    const int kk = blockIdx.x;           // 0..2047
    const int j = kk >> 8, k = kk & 255;
    const int n = threadIdx.x;
    ((unsigned short*)T8)[(size_t)n * 2048 + j * 256 + k] = f2bf(p.m[j][(size_t)k * 256 + n]);
}

// cK8 = bK (I + W + ... + W^7), via cK2 -> cK4 -> cK8 doubling
__global__ __launch_bounds__(256) void ck8k(
    const float* __restrict__ bK, const float* __restrict__ W,
    const float* __restrict__ W2, const float* __restrict__ W4,
    float* __restrict__ cK8)
{
    __shared__ float t[256];
    const int col = threadIdx.x;
    float v = bK[col];
    for (int k = 0; k < 256; ++k) v += bK[k] * W[(size_t)k * 256 + col];
    t[col] = v; __syncthreads();
    float v2 = v;
    for (int k = 0; k < 256; ++k) v2 += t[k] * W2[(size_t)k * 256 + col];
    __syncthreads(); t[col] = v2; __syncthreads();
    float v3 = v2;
    for (int k = 0; k < 256; ++k) v3 += t[k] * W4[(size_t)k * 256 + col];
    cK8[col] = v3;
}

// stash[b][p][col] = bK[col] + uu[b][p] . WB[:,col]   (p = 0..6 -> c_{p+1})
__global__ __launch_bounds__(256) void stashk7(
    const __hip_bfloat16* __restrict__ u_bf, const __hip_bfloat16* __restrict__ v,
    const __hip_bfloat16* __restrict__ WBT, const float* __restrict__ bK,
    float* __restrict__ stash)
{
    __shared__ float uuL[7][256];
    const int b = blockIdx.x;            // 0..511
    const int tid = threadIdx.x;
    #pragma unroll
    for (int p = 0; p < 7; ++p) {
        float val;
        if (tid < 64) val = bf2f(((const unsigned short*)u_bf)[((size_t)b * 256 + p) * 64 + tid]);
        else          val = bf2f(((const unsigned short*)v)[((size_t)b * 256 + p) * 192 + tid - 64]);
        uuL[p][tid] = val;
    }
    __syncthreads();
    const int col = tid;
    float a[7];
    #pragma unroll
    for (int p = 0; p < 7; ++p) a[p] = bK[col];
    for (int k = 0; k < 256; ++k) {
        const float w = bf2f(((const unsigned short*)WBT)[(size_t)col * 256 + k]);
        #pragma unroll
        for (int p = 0; p < 7; ++p) a[p] += uuL[p][k] * w;
    }
    #pragma unroll
    for (int p = 0; p < 7; ++p)
        stash[((size_t)b * 7 + p) * 256 + col] = a[p];
}

// ===========================================================================
// FUSED feedforward chains (r8 versions, measured-good).
// ===========================================================================
__global__ __launch_bounds__(512) void ffx(
    const __hip_bfloat16* __restrict__ x_bf,
    const __hip_bfloat16* __restrict__ W1T, const float* __restrict__ b1,
    const __hip_bfloat16* __restrict__ W2T, const float* __restrict__ b2,
    const __hip_bfloat16* __restrict__ W3T,
    float* __restrict__ y)
{
    __shared__ __align__(16) __hip_bfloat16 I[128 * 256];
    __shared__ __align__(16) __hip_bfloat16 Bs[256 * 32];
    __shared__ __align__(16) __hip_bfloat16 As[128 * 32];

    const int tid  = threadIdx.x;
    const int lane = tid & 63;
    const int wid  = tid >> 6;
    const int wm   = wid & 1;
    const int wn   = wid >> 1;
    const int row0 = blockIdx.x * 128;
    const int rlow = lane & 15;
    const int c    = lane >> 4;

    f32x4 acc[4][4];

    #pragma unroll
    for (int mi = 0; mi < 4; ++mi)
        #pragma unroll
        for (int ni = 0; ni < 4; ++ni)
            acc[mi][ni] = {0.f, 0.f, 0.f, 0.f};

    for (int k0 = 0; k0 < 64; k0 += 32) {
        {
            const int i = tid;
            const int row = i >> 2;
            const int cl  = (i & 3) ^ ((row >> 1) & 3);
            __builtin_amdgcn_global_load_lds(
                GLP(x_bf + (size_t)(row0 + row) * 64 + k0 + cl * 8),
                LDSP(As + i * 8), 16, 0, 0);
        }
        #pragma unroll
        for (int r = 0; r < 2; ++r) {
            const int i = r * 512 + tid;
            const int row = i >> 2;
            const int cl  = (i & 3) ^ ((row >> 1) & 3);
            __builtin_amdgcn_global_load_lds(
                GLP(W1T + (size_t)row * 64 + k0 + cl * 8),
                LDSP(Bs + i * 8), 16, 0, 0);
        }
        __syncthreads();
        short8 af[4], bfr[4];
        #pragma unroll
        for (int mi = 0; mi < 4; ++mi) {
            const int row  = wm * 64 + mi * 16 + rlow;
            const int phys = c ^ ((row >> 1) & 3);
            af[mi] = *(const short8*)((const char*)As + row * 64 + phys * 16);
        }
        #pragma unroll
        for (int ni = 0; ni < 4; ++ni) {
            const int row  = wn * 64 + ni * 16 + rlow;
            const int phys = c ^ ((row >> 1) & 3);
            bfr[ni] = *(const short8*)((const char*)Bs + row * 64 + phys * 16);
        }
        #pragma unroll
        for (int mi = 0; mi < 4; ++mi)
            #pragma unroll
            for (int ni = 0; ni < 4; ++ni)
                acc[mi][ni] = __builtin_amdgcn_mfma_f32_16x16x32_bf16(
                    af[mi], bfr[ni], acc[mi][ni], 0, 0, 0);
        __syncthreads();
    }
    #pragma unroll
    for (int ni = 0; ni < 4; ++ni) {
        const int col = wn * 64 + ni * 16 + rlow;
        const float bv = b1[col];
        #pragma unroll
        for (int mi = 0; mi < 4; ++mi)
            #pragma unroll
            for (int q = 0; q < 4; ++q) {
                const int row = wm * 64 + mi * 16 + c * 4 + q;
                const int byte = (row * 512 + col * 2) ^ ((row & 7) << 4);
                *(unsigned short*)((char*)I + byte) = f2bf(fmaxf(acc[mi][ni][q] + bv, 0.f));
            }
    }
    __syncthreads();

    #pragma unroll
    for (int mi = 0; mi < 4; ++mi)
        #pragma unroll
        for (int ni = 0; ni < 4; ++ni)
            acc[mi][ni] = {0.f, 0.f, 0.f, 0.f};

    for (int k0 = 0; k0 < 256; k0 += 32) {
        #pragma unroll
        for (int r = 0; r < 2; ++r) {
            const int i = r * 512 + tid;
            const int row = i >> 2;
            const int cl  = (i & 3) ^ ((row >> 1) & 3);
            __builtin_amdgcn_global_load_lds(
                GLP(W2T + (size_t)row * 256 + k0 + cl * 8),
                LDSP(Bs + i * 8), 16, 0, 0);
        }
        __syncthreads();
        short8 af[4], bfr[4];
        #pragma unroll
        for (int mi = 0; mi < 4; ++mi) {
            const int row = wm * 64 + mi * 16 + rlow;
            const int off = (row * 512 + k0 * 2 + c * 16) ^ ((row & 7) << 4);
            af[mi] = *(const short8*)((const char*)I + off);
        }
        #pragma unroll
        for (int ni = 0; ni < 4; ++ni) {
            const int row  = wn * 64 + ni * 16 + rlow;
            const int phys = c ^ ((row >> 1) & 3);
            bfr[ni] = *(const short8*)((const char*)Bs + row * 64 + phys * 16);
        }
        #pragma unroll
        for (int mi = 0; mi < 4; ++mi)
            #pragma unroll
            for (int ni = 0; ni < 4; ++ni)
                acc[mi][ni] = __builtin_amdgcn_mfma_f32_16x16x32_bf16(
                    af[mi], bfr[ni], acc[mi][ni], 0, 0, 0);
        __syncthreads();
    }
    #pragma unroll
    for (int ni = 0; ni < 4; ++ni) {
        const int col = wn * 64 + ni * 16 + rlow;
        const float bv = b2[col];
        #pragma unroll
        for (int mi = 0; mi < 4; ++mi)
            #pragma unroll
            for (int q = 0; q < 4; ++q) {
                const int row = wm * 64 + mi * 16 + c * 4 + q;
                const int byte = (row * 512 + col * 2) ^ ((row & 7) << 4);
                *(unsigned short*)((char*)I + byte) = f2bf(fmaxf(acc[mi][ni][q] + bv, 0.f));
            }
    }
    __syncthreads();

    f32x4 a3[4][3];
    #pragma unroll
    for (int mi = 0; mi < 4; ++mi)
        #pragma unroll
        for (int ni = 0; ni < 3; ++ni)
            a3[mi][ni] = {0.f, 0.f, 0.f, 0.f};

    for (int k0 = 0; k0 < 256; k0 += 32) {
        #pragma unroll
        for (int r = 0; r < 2; ++r) {
            const int i = r * 512 + tid;
            if (i < 768) {
                const int row = i >> 2;
                const int cl  = (i & 3) ^ ((row >> 1) & 3);
                __builtin_amdgcn_global_load_lds(
                    GLP(W3T + (size_t)row * 256 + k0 + cl * 8),
                    LDSP(Bs + i * 8), 16, 0, 0);
            }
        }
        __syncthreads();
        short8 af[4], bfr[3];
        #pragma unroll
        for (int mi = 0; mi < 4; ++mi) {
            const int row = wm * 64 + mi * 16 + rlow;
            const int off = (row * 512 + k0 * 2 + c * 16) ^ ((row & 7) << 4);
            af[mi] = *(const short8*)((const char*)I + off);
        }
        #pragma unroll
        for (int ni = 0; ni < 3; ++ni) {
            const int row  = wn * 48 + ni * 16 + rlow;
            const int phys = c ^ ((row >> 1) & 3);
            bfr[ni] = *(const short8*)((const char*)Bs + row * 64 + phys * 16);
        }
        #pragma unroll
        for (int mi = 0; mi < 4; ++mi)
            #pragma unroll
            for (int ni = 0; ni < 3; ++ni)
                a3[mi][ni] = __builtin_amdgcn_mfma_f32_16x16x32_bf16(
                    af[mi], bfr[ni], a3[mi][ni], 0, 0, 0);
        __syncthreads();
    }
    #pragma unroll
    for (int ni = 0; ni < 3; ++ni) {
        const int col = wn * 48 + ni * 16 + rlow;
        #pragma unroll
        for (int mi = 0; mi < 4; ++mi)
            #pragma unroll
            for (int q = 0; q < 4; ++q) {
                const int row = row0 + wm * 64 + mi * 16 + c * 4 + q;
                y[(size_t)row * 256 + 64 + col] = a3[mi][ni][q];
            }
    }
}

__global__ __launch_bounds__(512) void ffu(
    const __hip_bfloat16* __restrict__ u_bf,
    const __hip_bfloat16* __restrict__ W1T, const float* __restrict__ b1,
    const __hip_bfloat16* __restrict__ W2T,
    __hip_bfloat16* __restrict__ vout)
{
    __shared__ __align__(16) __hip_bfloat16 I[128 * 256];
    __shared__ __align__(16) __hip_bfloat16 Bs[256 * 32];
    __shared__ __align__(16) __hip_bfloat16 As[128 * 32];

    const int tid  = threadIdx.x;
    const int lane = tid & 63;
    const int wid  = tid >> 6;
    const int wm   = wid & 1;
    const int wn   = wid >> 1;
    const int row0 = blockIdx.x * 128;
    const int rlow = lane & 15;
    const int c    = lane >> 4;

    f32x4 acc[4][4];
    #pragma unroll
    for (int mi = 0; mi < 4; ++mi)
        #pragma unroll
        for (int ni = 0; ni < 4; ++ni)
            acc[mi][ni] = {0.f, 0.f, 0.f, 0.f};

    for (int k0 = 0; k0 < 64; k0 += 32) {
        {
            const int i = tid;
            const int row = i >> 2;
            const int cl  = (i & 3) ^ ((row >> 1) & 3);
            __builtin_amdgcn_global_load_lds(
                GLP(u_bf + (size_t)(row0 + row) * 64 + k0 + cl * 8),
                LDSP(As + i * 8), 16, 0, 0);
        }
        #pragma unroll
        for (int r = 0; r < 2; ++r) {
            const int i = r * 512 + tid;
            const int row = i >> 2;
            const int cl  = (i & 3) ^ ((row >> 1) & 3);
            __builtin_amdgcn_global_load_lds(
                GLP(W1T + (size_t)row * 64 + k0 + cl * 8),
                LDSP(Bs + i * 8), 16, 0, 0);
        }
        __syncthreads();
        short8 af[4], bfr[4];
        #pragma unroll
        for (int mi = 0; mi < 4; ++mi) {
            const int row  = wm * 64 + mi * 16 + rlow;
            const int phys = c ^ ((row >> 1) & 3);
            af[mi] = *(const short8*)((const char*)As + row * 64 + phys * 16);
        }
        #pragma unroll
        for (int ni = 0; ni < 4; ++ni) {
            const int row  = wn * 64 + ni * 16 + rlow;
            const int phys = c ^ ((row >> 1) & 3);
            bfr[ni] = *(const short8*)((const char*)Bs + row * 64 + phys * 16);
        }
        #pragma unroll
        for (int mi = 0; mi < 4; ++mi)
            #pragma unroll
            for (int ni = 0; ni < 4; ++ni)
                acc[mi][ni] = __builtin_amdgcn_mfma_f32_16x16x32_bf16(
                    af[mi], bfr[ni], acc[mi][ni], 0, 0, 0);
        __syncthreads();
    }
    #pragma unroll
    for (int ni = 0; ni < 4; ++ni) {
        const int col = wn * 64 + ni * 16 + rlow;
        const float bv = b1[col];
        #pragma unroll
        for (int mi = 0; mi < 4; ++mi)
            #pragma unroll
            for (int q = 0; q < 4; ++q) {
                const int row = wm * 64 + mi * 16 + c * 4 + q;
                const int byte = (row * 512 + col * 2) ^ ((row & 7) << 4);
                *(unsigned short*)((char*)I + byte) = f2bf(fmaxf(acc[mi][ni][q] + bv, 0.f));
            }
    }
    __syncthreads();

    f32x4 a3[4][3];
    #pragma unroll
    for (int mi = 0; mi < 4; ++mi)
        #pragma unroll
        for (int ni = 0; ni < 3; ++ni)
            a3[mi][ni] = {0.f, 0.f, 0.f, 0.f};

    for (int k0 = 0; k0 < 256; k0 += 32) {
        #pragma unroll
        for (int r = 0; r < 2; ++r) {
            const int i = r * 512 + tid;
            if (i < 768) {
                const int row = i >> 2;
                const int cl  = (i & 3) ^ ((row >> 1) & 3);
                __builtin_amdgcn_global_load_lds(
                    GLP(W2T + (size_t)row * 256 + k0 + cl * 8),
                    LDSP(Bs + i * 8), 16, 0, 0);
            }
        }
        __syncthreads();
        short8 af[4], bfr[3];
        #pragma unroll
        for (int mi = 0; mi < 4; ++mi) {
            const int row = wm * 64 + mi * 16 + rlow;
            const int off = (row * 512 + k0 * 2 + c * 16) ^ ((row & 7) << 4);
            af[mi] = *(const short8*)((const char*)I + off);
        }
        #pragma unroll
        for (int ni = 0; ni < 3; ++ni) {
            const int row  = wn * 48 + ni * 16 + rlow;
            const int phys = c ^ ((row >> 1) & 3);
            bfr[ni] = *(const short8*)((const char*)Bs + row * 64 + phys * 16);
        }
        #pragma unroll
        for (int mi = 0; mi < 4; ++mi)
            #pragma unroll
            for (int ni = 0; ni < 3; ++ni)
                a3[mi][ni] = __builtin_amdgcn_mfma_f32_16x16x32_bf16(
                    af[mi], bfr[ni], a3[mi][ni], 0, 0, 0);
        __syncthreads();
    }
    #pragma unroll
    for (int ni = 0; ni < 3; ++ni) {
        const int col = wn * 48 + ni * 16 + rlow;
        #pragma unroll
        for (int mi = 0; mi < 4; ++mi)
            #pragma unroll
            for (int q = 0; q < 4; ++q) {
                const int row = row0 + wm * 64 + mi * 16 + c * 4 + q;
                ((unsigned short*)vout)[(size_t)row * 192 + col] = f2bf(a3[mi][ni][q]);
            }
    }
}

// ---------------------------------------------------------------------------
// D8 drive in ONE pass with A-panel reuse: stage 136-row panel once per
// 32-k chunk; 8 shift-sections read it at row offsets (7-j). B: 8 j-sections
// (64 KB). yp[r] (f32, t>=8) = cK8 + sum_{j=0..7} uu[r-1-j] @ (WB W^j).
// Same HBM traffic as the old K=1024 version; 2x MFMA (128 per barrier/wave).
// ---------------------------------------------------------------------------
__global__ __launch_bounds__(256) void d8g(
    const __hip_bfloat16* __restrict__ u_bf, const __hip_bfloat16* __restrict__ v,
    const __hip_bfloat16* __restrict__ WBT8, const float* __restrict__ cK8,
    float* __restrict__ yp)
{
    __shared__ __align__(16) __hip_bfloat16 As[136 * 32];     // 8.5 KB panel
    __shared__ __align__(16) __hip_bfloat16 Bs[8][128 * 32];  // 64 KB

    const int tid  = threadIdx.x;
    const int lane = tid & 63;
    const int wid  = tid >> 6;
    const int wm   = wid & 1;
    const int wn   = wid >> 1;
    const int row0 = blockIdx.x * 128;
    const int col0 = blockIdx.y * 128;
    const int rlow = lane & 15;
    const int c    = lane >> 4;

    f32x4 acc[4][4];
    #pragma unroll
    for (int mi = 0; mi < 4; ++mi)
        #pragma unroll
        for (int ni = 0; ni < 4; ++ni)
            acc[mi][ni] = {0.f, 0.f, 0.f, 0.f};

    for (int kl = 0; kl < 256; kl += 32) {
        const __hip_bfloat16* Ab; int Al, kk;
        if (kl < 64) { Ab = u_bf; Al = 64;  kk = kl; }
        else         { Ab = v;    Al = 192; kk = kl - 64; }

        // A panel: rows row0-8 .. row0+127  (panel row p -> global row0-8+p)
        #pragma unroll
        for (int r = 0; r < 3; ++r) {
            const int i = r * 256 + tid;            // 544 slots
            if (i < 544) {
                const int row = i >> 2;
                const int cl  = (i & 3) ^ ((row >> 1) & 3);
                int srow = row0 - 8 + row;
                if (srow < 0) srow = 0;             // feeds only guarded t<8 rows
                __builtin_amdgcn_global_load_lds(
                    GLP(Ab + (size_t)srow * Al + kk + cl * 8),
                    LDSP(As + i * 8), 16, 0, 0);
            }
        }
        // B: 8 j-sections x 128 rows x 32 k  (L2-resident, 1 MB matrix)
        #pragma unroll
        for (int r = 0; r < 16; ++r) {
            const int i = r * 256 + tid;            // 4096 slots
            const int j = i >> 9;
            const int s = i & 511;
            const int row = s >> 2;
            const int cl  = (s & 3) ^ ((row >> 1) & 3);
            __builtin_amdgcn_global_load_lds(
                GLP(WBT8 + (size_t)(col0 + row) * 2048 + j * 256 + kl + cl * 8),
                LDSP(&Bs[0][0] + i * 8), 16, 0, 0);
        }
        __syncthreads();

        #pragma unroll
        for (int j = 0; j < 8; ++j) {
            short8 bfr[4];
            #pragma unroll
            for (int ni = 0; ni < 4; ++ni) {
                const int row  = wn * 64 + ni * 16 + rlow;
                const int phys = c ^ ((row >> 1) & 3);
                bfr[ni] = *(const short8*)((const char*)Bs[j] + row * 64 + phys * 16);
            }
            #pragma unroll
            for (int mi = 0; mi < 4; ++mi) {
                const int prow = wm * 64 + mi * 16 + rlow + 7 - j;  // global r-1-j
                const int phys = c ^ ((prow >> 1) & 3);
                const short8 af = *(const short8*)((const char*)As + prow * 64 + phys * 16);
                #pragma unroll
                for (int ni = 0; ni < 4; ++ni)
                    acc[mi][ni] = __builtin_amdgcn_mfma_f32_16x16x32_bf16(
                        af, bfr[ni], acc[mi][ni], 0, 0, 0);
            }
        }
        __syncthreads();
    }

    const int q4 = lane >> 4;
    #pragma unroll
    for (int ni = 0; ni < 4; ++ni) {
        const int col = col0 + wn * 64 + ni * 16 + rlow;
        const float bv = cK8[col];
        #pragma unroll
        for (int mi = 0; mi < 4; ++mi) {
            #pragma unroll
            for (int q = 0; q < 4; ++q) {
                const int row = row0 + wm * 64 + mi * 16 + q4 * 4 + q;
                if ((row & 255) >= 8)
                    yp[(size_t)row * 256 + col] = acc[mi][ni][q] + bv;
            }
        }
    }
}

// ---------------------------------------------------------------------------
// gather hi/lo bf16 B-fragments of a 256x256 fp32 matrix
// ---------------------------------------------------------------------------
static __device__ __forceinline__ void gather_frags(
    const float* __restrict__ M, int col0, int rlow, int kg,
    short8 (&wh)[2][8], short8 (&wl)[2][8])
{
    #pragma unroll
    for (int tile = 0; tile < 2; ++tile) {
        const int col = col0 + tile * 16 + rlow;
        for (int kc = 0; kc < 8; ++kc) {
            const int k0 = kc * 32 + kg * 8;
            short8 h, l;
            for (int i = 0; i < 8; ++i) {
                const float w = M[(size_t)(k0 + i) * 256 + col];
                const unsigned short hb = f2bf(w);
                h[i] = (short)hb;
                l[i] = (short)f2bf(w - bf2f(hb));
            }
            wh[tile][kc] = h;
            wl[tile][kc] = l;
        }
    }
}

// ---------------------------------------------------------------------------
// Unrolled scan x8: y_t = y_{t-8}@W8 + D8[t], D8 f32 IN-PLACE in yp.
// 256 blocks (ALL CUs) x 8 waves; block owns 2 batches x 8 phases = 16 rows.
// Row semantic: row = phase*2 + b. Prologue: y_1..y_7 with W (stash c_p).
// Main: 31 super-steps, W8 hi/lo 3-pass, D prefetch 1 step ahead,
// LGKM-only barriers (global ops stay in flight).
// ---------------------------------------------------------------------------
__global__ __launch_bounds__(512, 1) void scan8(
    const float* __restrict__ WK, const float* __restrict__ W8,
    const float* __restrict__ stash,
    const float* __restrict__ y, float* __restrict__ yp)
{
    __shared__ __align__(16) __hip_bfloat16 cbuf[2][2][16 * 256];

    const int tid  = threadIdx.x;
    const int lane = tid & 63;
    const int wid  = tid >> 6;
    const int b0   = blockIdx.x * 2;
    const int col0 = wid * 32;
    const int rlow = lane & 15;
    const int kg   = lane >> 4;
    const int rswz = (rlow & 7) << 4;

    // init: rows 0,1 = y0 (phase 0, batches b0,b0+1); zero rows 2..15
    {
        const int b  = tid >> 8;         // 0..1
        const int cc = tid & 255;
        const float v = y[(size_t)(b0 + b) * 65536 + cc];
        yp[(size_t)(b0 + b) * 65536 + cc] = v;
        const unsigned short hb = f2bf(v);
        const unsigned short lb = f2bf(v - bf2f(hb));
        const int byte = (b * 512 + cc * 2) ^ ((b & 7) << 4);
        *(unsigned short*)((char*)&cbuf[0][0][0] + byte) = hb;
        *(unsigned short*)((char*)&cbuf[0][1][0] + byte) = lb;
        unsigned int* hz = (unsigned int*)((char*)&cbuf[0][0][0] + 1024);
        unsigned int* lz = (unsigned int*)((char*)&cbuf[0][1][0] + 1024);
        for (int i = tid; i < 1792; i += 512) { hz[i] = 0; lz[i] = 0; }
    }
    __syncthreads();

    short8 wh[2][8], wl[2][8];
    gather_frags(WK, col0, rlow, kg, wh, wl);

    // prologue p = 1..7: y_p = y_{p-1}@W + c_p   (rows 2p-2,2p-1 -> 2p,2p+1)
    for (int p = 1; p < 8; ++p) {
        f32x4 aHH[2], aHL[2], aLH[2];
        #pragma unroll
        for (int tile = 0; tile < 2; ++tile) {
            aHH[tile] = {0.f, 0.f, 0.f, 0.f};
            aHL[tile] = {0.f, 0.f, 0.f, 0.f};
            aLH[tile] = {0.f, 0.f, 0.f, 0.f};
        }
        const char* hbase = (const char*)&cbuf[0][0][0];
        const char* lbase = (const char*)&cbuf[0][1][0];
        #pragma unroll
        for (int kc = 0; kc < 8; ++kc) {
            const int off = (rlow * 512 + kg * 16 + kc * 64) ^ rswz;
            const short8 ah = *(const short8*)(hbase + off);
            const short8 al = *(const short8*)(lbase + off);
            aHH[0] = __builtin_amdgcn_mfma_f32_16x16x32_bf16(ah, wh[0][kc], aHH[0], 0, 0, 0);
            aHH[1] = __builtin_amdgcn_mfma_f32_16x16x32_bf16(ah, wh[1][kc], aHH[1], 0, 0, 0);
            aHL[0] = __builtin_amdgcn_mfma_f32_16x16x32_bf16(ah, wl[0][kc], aHL[0], 0, 0, 0);
            aHL[1] = __builtin_amdgcn_mfma_f32_16x16x32_bf16(ah, wl[1][kc], aHL[1], 0, 0, 0);
            aLH[0] = __builtin_amdgcn_mfma_f32_16x16x32_bf16(al, wh[0][kc], aLH[0], 0, 0, 0);
            aLH[1] = __builtin_amdgcn_mfma_f32_16x16x32_bf16(al, wh[1][kc], aLH[1], 0, 0, 0);
        }
        __builtin_amdgcn_sched_barrier(0);
        asm volatile("s_waitcnt lgkmcnt(0)" ::: "memory");
        __builtin_amdgcn_s_barrier();
        __builtin_amdgcn_sched_barrier(0);

        const int r0 = 2 * p - 2;
        if (kg == (r0 >> 2)) {
            #pragma unroll
            for (int tile = 0; tile < 2; ++tile) {
                const int col = col0 + tile * 16 + rlow;
                #pragma unroll
                for (int q = 0; q < 4; ++q) {
                    if ((q >> 1) == ((r0 & 3) >> 1)) {
                        const int b = q & 1;
                        const float cv = stash[((size_t)(b0 + b) * 7 + (p - 1)) * 256 + col];
                        const float yv = aHH[tile][q] + aHL[tile][q] + aLH[tile][q] + cv;
                        const int wr = 2 * p + b;
                        const unsigned short hb = f2bf(yv);
                        const unsigned short lb = f2bf(yv - bf2f(hb));
                        const int byte = (wr * 512 + col * 2) ^ ((wr & 7) << 4);
                        *(unsigned short*)((char*)&cbuf[0][0][0] + byte) = hb;
                        *(unsigned short*)((char*)&cbuf[0][1][0] + byte) = lb;
                        yp[(size_t)(b0 + b) * 65536 + (size_t)p * 256 + col] = yv;
                    }
                }
            }
        }
        __builtin_amdgcn_sched_barrier(0);
        asm volatile("s_waitcnt lgkmcnt(0)" ::: "memory");
        __builtin_amdgcn_s_barrier();
        __builtin_amdgcn_sched_barrier(0);
    }

    gather_frags(W8, col0, rlow, kg, wh, wl);

    // prefetch D8 for s=0  (row = kg*4+q -> phase kg*2+(q>>1), batch q&1)
    float dv[2][4];
    #pragma unroll
    for (int tile = 0; tile < 2; ++tile) {
        const int col = col0 + tile * 16 + rlow;
        #pragma unroll
        for (int q = 0; q < 4; ++q)
            dv[tile][q] = yp[(size_t)(b0 + (q & 1)) * 65536
                             + (size_t)(8 + kg * 2 + (q >> 1)) * 256 + col];
    }

    int cur = 0;
    for (int s = 0; s < 31; ++s) {
        const int tb = 8 + s * 8;

        float dn[2][4];
        if (s < 30) {
            #pragma unroll
            for (int tile = 0; tile < 2; ++tile) {
                const int col = col0 + tile * 16 + rlow;
                #pragma unroll
                for (int q = 0; q < 4; ++q)
                    dn[tile][q] = yp[(size_t)(b0 + (q & 1)) * 65536
                                     + (size_t)(tb + 8 + kg * 2 + (q >> 1)) * 256 + col];
            }
        }

        f32x4 aHH[2], aHL[2], aLH[2];
        #pragma unroll
        for (int tile = 0; tile < 2; ++tile) {
            aHH[tile] = {0.f, 0.f, 0.f, 0.f};
            aHL[tile] = {0.f, 0.f, 0.f, 0.f};
            aLH[tile] = {0.f, 0.f, 0.f, 0.f};
        }
        const char* hbase = (const char*)&cbuf[cur][0][0];
        const char* lbase = (const char*)&cbuf[cur][1][0];
        #pragma unroll
        for (int kc = 0; kc < 8; ++kc) {
            const int off = (rlow * 512 + kg * 16 + kc * 64) ^ rswz;
            const short8 ah = *(const short8*)(hbase + off);
            const short8 al = *(const short8*)(lbase + off);
            aHH[0] = __builtin_amdgcn_mfma_f32_16x16x32_bf16(ah, wh[0][kc], aHH[0], 0, 0, 0);
            aHH[1] = __builtin_amdgcn_mfma_f32_16x16x32_bf16(ah, wh[1][kc], aHH[1], 0, 0, 0);
            aHL[0] = __builtin_amdgcn_mfma_f32_16x16x32_bf16(ah, wl[0][kc], aHL[0], 0, 0, 0);
            aHL[1] = __builtin_amdgcn_mfma_f32_16x16x32_bf16(ah, wl[1][kc], aHL[1], 0, 0, 0);
            aLH[0] = __builtin_amdgcn_mfma_f32_16x16x32_bf16(al, wh[0][kc], aLH[0], 0, 0, 0);
            aLH[1] = __builtin_amdgcn_mfma_f32_16x16x32_bf16(al, wh[1][kc], aLH[1], 0, 0, 0);
        }

        char* whb = (char*)&cbuf[cur ^ 1][0][0];
        char* wlb = (char*)&cbuf[cur ^ 1][1][0];
        #pragma unroll
        for (int tile = 0; tile < 2; ++tile) {
            const int col = col0 + tile * 16 + rlow;
            #pragma unroll
            for (int q = 0; q < 4; ++q) {
                const int row = kg * 4 + q;             // = phase*2 + b
                const float yv = aHH[tile][q] + aHL[tile][q] + aLH[tile][q] + dv[tile][q];
                const unsigned short hb = f2bf(yv);
                const unsigned short lb = f2bf(yv - bf2f(hb));
                const int byte = (row * 512 + col * 2) ^ ((row & 7) << 4);
                *(unsigned short*)(whb + byte) = hb;
                *(unsigned short*)(wlb + byte) = lb;
                yp[(size_t)(b0 + (row & 1)) * 65536
                   + (size_t)(tb + (row >> 1)) * 256 + col] = yv;
            }
        }
        if (s < 30) {
            #pragma unroll
            for (int tile = 0; tile < 2; ++tile)
                #pragma unroll
                for (int q = 0; q < 4; ++q)
                    dv[tile][q] = dn[tile][q];
        }

        __builtin_amdgcn_sched_barrier(0);
        asm volatile("s_waitcnt lgkmcnt(0)" ::: "memory");
        __builtin_amdgcn_s_barrier();
        __builtin_amdgcn_sched_barrier(0);
        cur ^= 1;
    }
}

// ---------------------------------------------------------------------------
extern "C" void kernel_launch(void* const* d_in, const int* in_sizes, int n_in,
                              void* d_out, int out_size, void* d_ws, size_t ws_size,
                              hipStream_t stream)
{
    const float* x   = (const float*)d_in[0];
    const float* u   = (const float*)d_in[1];
    const float* Wx1 = (const float*)d_in[2];
    const float* bx1 = (const float*)d_in[3];
    const float* Wx2 = (const float*)d_in[4];
    const float* bx2 = (const float*)d_in[5];
    const float* Wx3 = (const float*)d_in[6];
    const float* Wu1 = (const float*)d_in[7];
    const float* bu1 = (const float*)d_in[8];
    const float* Wu2 = (const float*)d_in[9];
    const float* WB  = (const float*)d_in[10];
    const float* WK  = (const float*)d_in[11];
    const float* bK  = (const float*)d_in[12];

    float* y  = (float*)d_out;
    float* yp = y + (size_t)MM * 256;

    char* ws = (char*)d_ws;
    __hip_bfloat16* x_bf = (__hip_bfloat16*)(ws);
    __hip_bfloat16* u_bf = (__hip_bfloat16*)(ws + 16777216);
    __hip_bfloat16* wTb  = (__hip_bfloat16*)(ws + 33554432);
    __hip_bfloat16* Wx1T = wTb;
    __hip_bfloat16* Wx2T = wTb + 16384;
    __hip_bfloat16* Wx3T = wTb + 81920;
    __hip_bfloat16* Wu1T = wTb + 131072;
    __hip_bfloat16* Wu2T = wTb + 147456;
    __hip_bfloat16* WBT  = wTb + 196608;
    __hip_bfloat16* t2   = (__hip_bfloat16*)(ws + 34078720);     // v (M x 192)
    float* W2f   = (float*)(ws + 101187584);
    float* W4f   = (float*)(ws + 101449728);
    float* W8f   = (float*)(ws + 101711872);
    float* WBWf  = (float*)(ws + 101974016);
    float* WBW2f = (float*)(ws + 102236160);
    float* WBW3f = (float*)(ws + 102498304);
    float* WBW4f = (float*)(ws + 102760448);
    float* WBW5f = (float*)(ws + 103022592);
    float* WBW6f = (float*)(ws + 103284736);
    float* WBW7f = (float*)(ws + 103546880);
    __hip_bfloat16* WBT8 = (__hip_bfloat16*)(ws + 103809024);    // 1 MB
    float* cK8   = (float*)(ws + 104857600);
    float* stash = (float*)(ws + 104858624);                     // 3.67 MB

    dim3 blk(256);

    conv2_bf16<<<16384, blk, 0, stream>>>(x, u, x_bf, u_bf, y);
    wtrans_all<<<1024, blk, 0, stream>>>(Wx1, Wx2, Wx3, Wu1, Wu2, WB,
                                         Wx1T, Wx2T, Wx3T, Wu1T, Wu2T, WBT);

    // W-power products, 3 batched levels (depth-parallel)
    {
        G5 L1 = {{WK, WB, nullptr, nullptr, nullptr},
                 {WK, WK, nullptr, nullptr, nullptr},
                 {W2f, WBWf, nullptr, nullptr, nullptr}};
        wgemm<<<32, blk, 0, stream>>>(L1);
        G5 L2 = {{W2f, WB, WBWf, nullptr, nullptr},
                 {W2f, W2f, W2f, nullptr, nullptr},
                 {W4f, WBW2f, WBW3f, nullptr, nullptr}};
        wgemm<<<48, blk, 0, stream>>>(L2);
        G5 L3 = {{W4f, WB, WBWf, WBW2f, WBW3f},
                 {W4f, W4f, W4f, W4f, W4f},
                 {W8f, WBW4f, WBW5f, WBW6f, WBW7f}};
        wgemm<<<80, blk, 0, stream>>>(L3);
    }
    {
        P8 p = {{WB, WBWf, WBW2f, WBW3f, WBW4f, WBW5f, WBW6f, WBW7f}};
        bigbt8<<<2048, blk, 0, stream>>>(p, WBT8);
    }
    ck8k<<<1, blk, 0, stream>>>(bK, WK, W2f, W4f, cK8);

    // fused feedforward chains
    ffx<<<1024, dim3(512), 0, stream>>>(x_bf, Wx1T, bx1, Wx2T, bx2, Wx3T, y);
    ffu<<<1024, dim3(512), 0, stream>>>(u_bf, Wu1T, bu1, Wu2T, t2);

    // prologue constants + single-pass D8 (f32, in-place in yp, t>=8)
    stashk7<<<512, blk, 0, stream>>>(u_bf, t2, WBT, bK, stash);
    d8g<<<dim3(1024, 2), blk, 0, stream>>>(u_bf, t2, WBT8, cK8, yp);

    // unrolled recurrence (31 super-steps, 256 blocks)
    scan8<<<256, dim3(512), 0, stream>>>(WK, W8f, stash, y, yp);
}

// Round 12
// 403.025 us; speedup vs baseline: 1.4087x; 1.4087x over previous
//
#include <hip/hip_runtime.h>
#include <hip/hip_bf16.h>

#define MM 131072

typedef __attribute__((ext_vector_type(8))) short short8;
typedef __attribute__((ext_vector_type(4))) float f32x4;

#define GLP(p) (const __attribute__((address_space(1))) void*)(p)
#define LDSP(p) (__attribute__((address_space(3))) void*)(p)

static __device__ __forceinline__ unsigned short f2bf(float f) {
    union { float f; unsigned int u; } v; v.f = f;
    unsigned int r = v.u + 0x7FFF + ((v.u >> 16) & 1);  // RNE
    return (unsigned short)(r >> 16);
}
static __device__ __forceinline__ float bf2f(unsigned short h) {
    union { float f; unsigned int u; } v; v.u = ((unsigned int)h) << 16;
    return v.f;
}

// ---------------------------------------------------------------------------
// prep0: fused {fp32->bf16 conv for x,u + x copy into y} and {6x W -> WT bf16}
// blocks 0..16383: conv ; 16384..17407: wtrans
// ---------------------------------------------------------------------------
__global__ __launch_bounds__(256) void prep0(
    const float* __restrict__ x, const float* __restrict__ u,
    __hip_bfloat16* __restrict__ xb, __hip_bfloat16* __restrict__ ub,
    float* __restrict__ y,
    const float* __restrict__ W0, const float* __restrict__ W1,
    const float* __restrict__ W2, const float* __restrict__ W3,
    const float* __restrict__ W4, const float* __restrict__ W5,
    __hip_bfloat16* __restrict__ T0, __hip_bfloat16* __restrict__ T1,
    __hip_bfloat16* __restrict__ T2, __hip_bfloat16* __restrict__ T3,
    __hip_bfloat16* __restrict__ T4, __hip_bfloat16* __restrict__ T5)
{
    if (blockIdx.x < 16384) {
        int i = blockIdx.x * 256 + threadIdx.x;
        const float* s; __hip_bfloat16* d; int j; bool isx;
        if (i < 2097152) { s = x; d = xb; j = i; isx = true; }
        else             { s = u; d = ub; j = i - 2097152; isx = false; }
        const float4 v = ((const float4*)s)[j];
        union { unsigned short h[4]; uint2 u2; } p;
        p.h[0] = f2bf(v.x); p.h[1] = f2bf(v.y);
        p.h[2] = f2bf(v.z); p.h[3] = f2bf(v.w);
        ((uint2*)d)[j] = p.u2;
        if (isx) {
            const int r = j >> 4, q = j & 15;
            ((float4*)(y + (size_t)r * 256))[q] = v;
        }
    } else {
        const int b = blockIdx.x - 16384;
        const float* W; __hip_bfloat16* T; int K, N, i0;
        if      (b < 64)  { W = W0; T = T0; K = 64;  N = 256; i0 = b; }
        else if (b < 320) { W = W1; T = T1; K = 256; N = 256; i0 = b - 64; }
        else if (b < 512) { W = W2; T = T2; K = 256; N = 192; i0 = b - 320; }
        else if (b < 576) { W = W3; T = T3; K = 64;  N = 256; i0 = b - 512; }
        else if (b < 768) { W = W4; T = T4; K = 256; N = 192; i0 = b - 576; }
        else              { W = W5; T = T5; K = 256; N = 256; i0 = b - 768; }
        const int i = i0 * 256 + threadIdx.x;
        if (i < K * N) {
            const int n = i / K, k = i - n * K;
            T[i] = __float2bfloat16(W[(size_t)k * N + n]);
        }
    }
}

// ---------------------------------------------------------------------------
// Batched fp32 256x256x256 GEMMs for W-power products (up to 5 per launch).
// ---------------------------------------------------------------------------
struct G5 { const float* a[5]; const float* b[5]; float* c[5]; };

__global__ __launch_bounds__(256) void wgemm(G5 P)
{
    __shared__ __align__(16) float As[16][68];
    __shared__ __align__(16) float Ws[16][64];

    const int e  = blockIdx.x >> 4;
    const int tl = blockIdx.x & 15;
    const float* A = P.a[e];
    const float* W = P.b[e];
    float*       C = P.c[e];
    const int row0 = (tl >> 2) * 64;
    const int col0 = (tl & 3) * 64;

    const int tx = threadIdx.x & 15;
    const int ty = threadIdx.x >> 4;

    float acc[4][4] = {};

    for (int k0 = 0; k0 < 256; k0 += 16) {
        {
            const int kk = threadIdx.x & 15;
            const int r  = threadIdx.x >> 4;
            #pragma unroll
            for (int rr = 0; rr < 4; ++rr)
                As[kk][r + rr * 16] = A[(size_t)(row0 + r + rr * 16) * 256 + k0 + kk];
        }
        {
            const int n  = threadIdx.x & 63;
            const int kz = threadIdx.x >> 6;
            #pragma unroll
            for (int kq = 0; kq < 4; ++kq) {
                const int kk = kz + kq * 4;
                Ws[kk][n] = W[(size_t)(k0 + kk) * 256 + col0 + n];
            }
        }
        __syncthreads();
        #pragma unroll
        for (int kk = 0; kk < 16; ++kk) {
            const float4 a4 = *(const float4*)&As[kk][ty * 4];
            const float4 w4 = *(const float4*)&Ws[kk][tx * 4];
            const float av[4] = {a4.x, a4.y, a4.z, a4.w};
            const float wv[4] = {w4.x, w4.y, w4.z, w4.w};
            #pragma unroll
            for (int i = 0; i < 4; ++i)
                #pragma unroll
                for (int j = 0; j < 4; ++j)
                    acc[i][j] += av[i] * wv[j];
        }
        __syncthreads();
    }

    #pragma unroll
    for (int i = 0; i < 4; ++i)
        #pragma unroll
        for (int j = 0; j < 4; ++j)
            C[(size_t)(row0 + ty * 4 + i) * 256 + col0 + tx * 4 + j] = acc[i][j];
}

// ---------------------------------------------------------------------------
// bigbt_ck: blocks 0..1023 build WBT4[n][j*256+k]; block 1024 computes
// cK4 = bK (I + W + W^2 + W^3).
// ---------------------------------------------------------------------------
__global__ __launch_bounds__(256) void bigbt_ck(
    const float* __restrict__ WB, const float* __restrict__ WBW,
    const float* __restrict__ WBW2, const float* __restrict__ WBW3,
    __hip_bfloat16* __restrict__ T4,
    const float* __restrict__ bK, const float* __restrict__ W,
    const float* __restrict__ W2, const float* __restrict__ W3,
    float* __restrict__ cK4)
{
    if (blockIdx.x < 1024) {
        const int kk = blockIdx.x;
        const int j = kk >> 8, k = kk & 255;
        const float* src = (j == 0) ? WB : (j == 1) ? WBW : (j == 2) ? WBW2 : WBW3;
        const int n = threadIdx.x;
        ((unsigned short*)T4)[(size_t)n * 1024 + kk] = f2bf(src[(size_t)k * 256 + n]);
    } else {
        const int col = threadIdx.x;
        float s = bK[col];
        for (int k = 0; k < 256; ++k)
            s += bK[k] * (W[(size_t)k * 256 + col] + W2[(size_t)k * 256 + col]
                          + W3[(size_t)k * 256 + col]);
        cK4[col] = s;
    }
}

// stash[b][p][col] = bK[col] + uu[b][p] . WB[:,col]   (p = 0..2 -> c_{p+1})
__global__ __launch_bounds__(256) void stashk(
    const __hip_bfloat16* __restrict__ u_bf, const __hip_bfloat16* __restrict__ v,
    const __hip_bfloat16* __restrict__ WBT, const float* __restrict__ bK,
    float* __restrict__ stash)
{
    __shared__ float uuL[3][256];
    const int b = blockIdx.x;            // 0..511
    const int tid = threadIdx.x;
    #pragma unroll
    for (int p = 0; p < 3; ++p) {
        float val;
        if (tid < 64) val = bf2f(((const unsigned short*)u_bf)[((size_t)b * 256 + p) * 64 + tid]);
        else          val = bf2f(((const unsigned short*)v)[((size_t)b * 256 + p) * 192 + tid - 64]);
        uuL[p][tid] = val;
    }
    __syncthreads();
    const int col = tid;
    float a0 = bK[col], a1 = a0, a2 = a0;
    for (int k = 0; k < 256; ++k) {
        const float w = bf2f(((const unsigned short*)WBT)[(size_t)col * 256 + k]);
        a0 += uuL[0][k] * w;
        a1 += uuL[1][k] * w;
        a2 += uuL[2][k] * w;
    }
    stash[((size_t)b * 3 + 0) * 256 + col] = a0;
    stash[((size_t)b * 3 + 1) * 256 + col] = a1;
    stash[((size_t)b * 3 + 2) * 256 + col] = a2;
}

// ===========================================================================
// FUSED feedforward chains (r8/r10 versions, measured-good).
// ===========================================================================
__global__ __launch_bounds__(512) void ffx(
    const __hip_bfloat16* __restrict__ x_bf,
    const __hip_bfloat16* __restrict__ W1T, const float* __restrict__ b1,
    const __hip_bfloat16* __restrict__ W2T, const float* __restrict__ b2,
    const __hip_bfloat16* __restrict__ W3T,
    float* __restrict__ y)
{
    __shared__ __align__(16) __hip_bfloat16 I[128 * 256];
    __shared__ __align__(16) __hip_bfloat16 Bs[256 * 32];
    __shared__ __align__(16) __hip_bfloat16 As[128 * 32];

    const int tid  = threadIdx.x;
    const int lane = tid & 63;
    const int wid  = tid >> 6;
    const int wm   = wid & 1;
    const int wn   = wid >> 1;
    const int row0 = blockIdx.x * 128;
    const int rlow = lane & 15;
    const int c    = lane >> 4;

    f32x4 acc[4][4];

    #pragma unroll
    for (int mi = 0; mi < 4; ++mi)
        #pragma unroll
        for (int ni = 0; ni < 4; ++ni)
            acc[mi][ni] = {0.f, 0.f, 0.f, 0.f};

    for (int k0 = 0; k0 < 64; k0 += 32) {
        {
            const int i = tid;
            const int row = i >> 2;
            const int cl  = (i & 3) ^ ((row >> 1) & 3);
            __builtin_amdgcn_global_load_lds(
                GLP(x_bf + (size_t)(row0 + row) * 64 + k0 + cl * 8),
                LDSP(As + i * 8), 16, 0, 0);
        }
        #pragma unroll
        for (int r = 0; r < 2; ++r) {
            const int i = r * 512 + tid;
            const int row = i >> 2;
            const int cl  = (i & 3) ^ ((row >> 1) & 3);
            __builtin_amdgcn_global_load_lds(
                GLP(W1T + (size_t)row * 64 + k0 + cl * 8),
                LDSP(Bs + i * 8), 16, 0, 0);
        }
        __syncthreads();
        short8 af[4], bfr[4];
        #pragma unroll
        for (int mi = 0; mi < 4; ++mi) {
            const int row  = wm * 64 + mi * 16 + rlow;
            const int phys = c ^ ((row >> 1) & 3);
            af[mi] = *(const short8*)((const char*)As + row * 64 + phys * 16);
        }
        #pragma unroll
        for (int ni = 0; ni < 4; ++ni) {
            const int row  = wn * 64 + ni * 16 + rlow;
            const int phys = c ^ ((row >> 1) & 3);
            bfr[ni] = *(const short8*)((const char*)Bs + row * 64 + phys * 16);
        }
        #pragma unroll
        for (int mi = 0; mi < 4; ++mi)
            #pragma unroll
            for (int ni = 0; ni < 4; ++ni)
                acc[mi][ni] = __builtin_amdgcn_mfma_f32_16x16x32_bf16(
                    af[mi], bfr[ni], acc[mi][ni], 0, 0, 0);
        __syncthreads();
    }
    #pragma unroll
    for (int ni = 0; ni < 4; ++ni) {
        const int col = wn * 64 + ni * 16 + rlow;
        const float bv = b1[col];
        #pragma unroll
        for (int mi = 0; mi < 4; ++mi)
            #pragma unroll
            for (int q = 0; q < 4; ++q) {
                const int row = wm * 64 + mi * 16 + c * 4 + q;
                const int byte = (row * 512 + col * 2) ^ ((row & 7) << 4);
                *(unsigned short*)((char*)I + byte) = f2bf(fmaxf(acc[mi][ni][q] + bv, 0.f));
            }
    }
    __syncthreads();

    #pragma unroll
    for (int mi = 0; mi < 4; ++mi)
        #pragma unroll
        for (int ni = 0; ni < 4; ++ni)
            acc[mi][ni] = {0.f, 0.f, 0.f, 0.f};

    for (int k0 = 0; k0 < 256; k0 += 32) {
        #pragma unroll
        for (int r = 0; r < 2; ++r) {
            const int i = r * 512 + tid;
            const int row = i >> 2;
            const int cl  = (i & 3) ^ ((row >> 1) & 3);
            __builtin_amdgcn_global_load_lds(
                GLP(W2T + (size_t)row * 256 + k0 + cl * 8),
                LDSP(Bs + i * 8), 16, 0, 0);
        }
        __syncthreads();
        short8 af[4], bfr[4];
        #pragma unroll
        for (int mi = 0; mi < 4; ++mi) {
            const int row = wm * 64 + mi * 16 + rlow;
            const int off = (row * 512 + k0 * 2 + c * 16) ^ ((row & 7) << 4);
            af[mi] = *(const short8*)((const char*)I + off);
        }
        #pragma unroll
        for (int ni = 0; ni < 4; ++ni) {
            const int row  = wn * 64 + ni * 16 + rlow;
            const int phys = c ^ ((row >> 1) & 3);
            bfr[ni] = *(const short8*)((const char*)Bs + row * 64 + phys * 16);
        }
        #pragma unroll
        for (int mi = 0; mi < 4; ++mi)
            #pragma unroll
            for (int ni = 0; ni < 4; ++ni)
                acc[mi][ni] = __builtin_amdgcn_mfma_f32_16x16x32_bf16(
                    af[mi], bfr[ni], acc[mi][ni], 0, 0, 0);
        __syncthreads();
    }
    #pragma unroll
    for (int ni = 0; ni < 4; ++ni) {
        const int col = wn * 64 + ni * 16 + rlow;
        const float bv = b2[col];
        #pragma unroll
        for (int mi = 0; mi < 4; ++mi)
            #pragma unroll
            for (int q = 0; q < 4; ++q) {
                const int row = wm * 64 + mi * 16 + c * 4 + q;
                const int byte = (row * 512 + col * 2) ^ ((row & 7) << 4);
                *(unsigned short*)((char*)I + byte) = f2bf(fmaxf(acc[mi][ni][q] + bv, 0.f));
            }
    }
    __syncthreads();

    f32x4 a3[4][3];
    #pragma unroll
    for (int mi = 0; mi < 4; ++mi)
        #pragma unroll
        for (int ni = 0; ni < 3; ++ni)
            a3[mi][ni] = {0.f, 0.f, 0.f, 0.f};

    for (int k0 = 0; k0 < 256; k0 += 32) {
        #pragma unroll
        for (int r = 0; r < 2; ++r) {
            const int i = r * 512 + tid;
            if (i < 768) {
                const int row = i >> 2;
                const int cl  = (i & 3) ^ ((row >> 1) & 3);
                __builtin_amdgcn_global_load_lds(
                    GLP(W3T + (size_t)row * 256 + k0 + cl * 8),
                    LDSP(Bs + i * 8), 16, 0, 0);
            }
        }
        __syncthreads();
        short8 af[4], bfr[3];
        #pragma unroll
        for (int mi = 0; mi < 4; ++mi) {
            const int row = wm * 64 + mi * 16 + rlow;
            const int off = (row * 512 + k0 * 2 + c * 16) ^ ((row & 7) << 4);
            af[mi] = *(const short8*)((const char*)I + off);
        }
        #pragma unroll
        for (int ni = 0; ni < 3; ++ni) {
            const int row  = wn * 48 + ni * 16 + rlow;
            const int phys = c ^ ((row >> 1) & 3);
            bfr[ni] = *(const short8*)((const char*)Bs + row * 64 + phys * 16);
        }
        #pragma unroll
        for (int mi = 0; mi < 4; ++mi)
            #pragma unroll
            for (int ni = 0; ni < 3; ++ni)
                a3[mi][ni] = __builtin_amdgcn_mfma_f32_16x16x32_bf16(
                    af[mi], bfr[ni], a3[mi][ni], 0, 0, 0);
        __syncthreads();
    }
    #pragma unroll
    for (int ni = 0; ni < 3; ++ni) {
        const int col = wn * 48 + ni * 16 + rlow;
        #pragma unroll
        for (int mi = 0; mi < 4; ++mi)
            #pragma unroll
            for (int q = 0; q < 4; ++q) {
                const int row = row0 + wm * 64 + mi * 16 + c * 4 + q;
                y[(size_t)row * 256 + 64 + col] = a3[mi][ni][q];
            }
    }
}

__global__ __launch_bounds__(512) void ffu(
    const __hip_bfloat16* __restrict__ u_bf,
    const __hip_bfloat16* __restrict__ W1T, const float* __restrict__ b1,
    const __hip_bfloat16* __restrict__ W2T,
    __hip_bfloat16* __restrict__ vout)
{
    __shared__ __align__(16) __hip_bfloat16 I[128 * 256];
    __shared__ __align__(16) __hip_bfloat16 Bs[256 * 32];
    __shared__ __align__(16) __hip_bfloat16 As[128 * 32];

    const int tid  = threadIdx.x;
    const int lane = tid & 63;
    const int wid  = tid >> 6;
    const int wm   = wid & 1;
    const int wn   = wid >> 1;
    const int row0 = blockIdx.x * 128;
    const int rlow = lane & 15;
    const int c    = lane >> 4;

    f32x4 acc[4][4];
    #pragma unroll
    for (int mi = 0; mi < 4; ++mi)
        #pragma unroll
        for (int ni = 0; ni < 4; ++ni)
            acc[mi][ni] = {0.f, 0.f, 0.f, 0.f};

    for (int k0 = 0; k0 < 64; k0 += 32) {
        {
            const int i = tid;
            const int row = i >> 2;
            const int cl  = (i & 3) ^ ((row >> 1) & 3);
            __builtin_amdgcn_global_load_lds(
                GLP(u_bf + (size_t)(row0 + row) * 64 + k0 + cl * 8),
                LDSP(As + i * 8), 16, 0, 0);
        }
        #pragma unroll
        for (int r = 0; r < 2; ++r) {
            const int i = r * 512 + tid;
            const int row = i >> 2;
            const int cl  = (i & 3) ^ ((row >> 1) & 3);
            __builtin_amdgcn_global_load_lds(
                GLP(W1T + (size_t)row * 64 + k0 + cl * 8),
                LDSP(Bs + i * 8), 16, 0, 0);
        }
        __syncthreads();
        short8 af[4], bfr[4];
        #pragma unroll
        for (int mi = 0; mi < 4; ++mi) {
            const int row  = wm * 64 + mi * 16 + rlow;
            const int phys = c ^ ((row >> 1) & 3);
            af[mi] = *(const short8*)((const char*)As + row * 64 + phys * 16);
        }
        #pragma unroll
        for (int ni = 0; ni < 4; ++ni) {
            const int row  = wn * 64 + ni * 16 + rlow;
            const int phys = c ^ ((row >> 1) & 3);
            bfr[ni] = *(const short8*)((const char*)Bs + row * 64 + phys * 16);
        }
        #pragma unroll
        for (int mi = 0; mi < 4; ++mi)
            #pragma unroll
            for (int ni = 0; ni < 4; ++ni)
                acc[mi][ni] = __builtin_amdgcn_mfma_f32_16x16x32_bf16(
                    af[mi], bfr[ni], acc[mi][ni], 0, 0, 0);
        __syncthreads();
    }
    #pragma unroll
    for (int ni = 0; ni < 4; ++ni) {
        const int col = wn * 64 + ni * 16 + rlow;
        const float bv = b1[col];
        #pragma unroll
        for (int mi = 0; mi < 4; ++mi)
            #pragma unroll
            for (int q = 0; q < 4; ++q) {
                const int row = wm * 64 + mi * 16 + c * 4 + q;
                const int byte = (row * 512 + col * 2) ^ ((row & 7) << 4);
                *(unsigned short*)((char*)I + byte) = f2bf(fmaxf(acc[mi][ni][q] + bv, 0.f));
            }
    }
    __syncthreads();

    f32x4 a3[4][3];
    #pragma unroll
    for (int mi = 0; mi < 4; ++mi)
        #pragma unroll
        for (int ni = 0; ni < 3; ++ni)
            a3[mi][ni] = {0.f, 0.f, 0.f, 0.f};

    for (int k0 = 0; k0 < 256; k0 += 32) {
        #pragma unroll
        for (int r = 0; r < 2; ++r) {
            const int i = r * 512 + tid;
            if (i < 768) {
                const int row = i >> 2;
                const int cl  = (i & 3) ^ ((row >> 1) & 3);
                __builtin_amdgcn_global_load_lds(
                    GLP(W2T + (size_t)row * 256 + k0 + cl * 8),
                    LDSP(Bs + i * 8), 16, 0, 0);
            }
        }
        __syncthreads();
        short8 af[4], bfr[3];
        #pragma unroll
        for (int mi = 0; mi < 4; ++mi) {
            const int row = wm * 64 + mi * 16 + rlow;
            const int off = (row * 512 + k0 * 2 + c * 16) ^ ((row & 7) << 4);
            af[mi] = *(const short8*)((const char*)I + off);
        }
        #pragma unroll
        for (int ni = 0; ni < 3; ++ni) {
            const int row  = wn * 48 + ni * 16 + rlow;
            const int phys = c ^ ((row >> 1) & 3);
            bfr[ni] = *(const short8*)((const char*)Bs + row * 64 + phys * 16);
        }
        #pragma unroll
        for (int mi = 0; mi < 4; ++mi)
            #pragma unroll
            for (int ni = 0; ni < 3; ++ni)
                a3[mi][ni] = __builtin_amdgcn_mfma_f32_16x16x32_bf16(
                    af[mi], bfr[ni], a3[mi][ni], 0, 0, 0);
        __syncthreads();
    }
    #pragma unroll
    for (int ni = 0; ni < 3; ++ni) {
        const int col = wn * 48 + ni * 16 + rlow;
        #pragma unroll
        for (int mi = 0; mi < 4; ++mi)
            #pragma unroll
            for (int q = 0; q < 4; ++q) {
                const int row = row0 + wm * 64 + mi * 16 + c * 4 + q;
                ((unsigned short*)vout)[(size_t)row * 192 + col] = f2bf(a3[mi][ni][q]);
            }
    }
}

// ---------------------------------------------------------------------------
// D4 drive, A-PANEL REUSE (r10, measured-good): stage 132-row A panel once
// per 32-k step; 4 shift-sections read it at row offsets (3-j).
// yp[r] (f32, t>=4) = cK4 + sum_j uu[r-1-j] @ WBpow_j.
// ---------------------------------------------------------------------------
__global__ __launch_bounds__(256) void d4g(
    const __hip_bfloat16* __restrict__ u_bf, const __hip_bfloat16* __restrict__ v,
    const __hip_bfloat16* __restrict__ WBT4, const float* __restrict__ cK4,
    float* __restrict__ yp)
{
    __shared__ __align__(16) __hip_bfloat16 As[132 * 32];
    __shared__ __align__(16) __hip_bfloat16 Bs[4][128 * 32];

    const int tid  = threadIdx.x;
    const int lane = tid & 63;
    const int wid  = tid >> 6;
    const int wm   = wid & 1;
    const int wn   = wid >> 1;
    const int row0 = blockIdx.x * 128;
    const int col0 = blockIdx.y * 128;
    const int rlow = lane & 15;
    const int c    = lane >> 4;

    f32x4 acc[4][4];
    #pragma unroll
    for (int mi = 0; mi < 4; ++mi)
        #pragma unroll
        for (int ni = 0; ni < 4; ++ni)
            acc[mi][ni] = {0.f, 0.f, 0.f, 0.f};

    for (int kl = 0; kl < 256; kl += 32) {
        const __hip_bfloat16* Ab; int Al, kk;
        if (kl < 64) { Ab = u_bf; Al = 64;  kk = kl; }
        else         { Ab = v;    Al = 192; kk = kl - 64; }

        #pragma unroll
        for (int r = 0; r < 3; ++r) {
            const int i = r * 256 + tid;
            if (i < 528) {
                const int row = i >> 2;
                const int cl  = (i & 3) ^ ((row >> 1) & 3);
                int srow = row0 - 4 + row;
                if (srow < 0) srow = 0;
                __builtin_amdgcn_global_load_lds(
                    GLP(Ab + (size_t)srow * Al + kk + cl * 8),
                    LDSP(As + i * 8), 16, 0, 0);
            }
        }
        #pragma unroll
        for (int r = 0; r < 8; ++r) {
            const int i = r * 256 + tid;
            const int j = i >> 9;
            const int s = i & 511;
            const int row = s >> 2;
            const int cl  = (s & 3) ^ ((row >> 1) & 3);
            __builtin_amdgcn_global_load_lds(
                GLP(WBT4 + (size_t)(col0 + row) * 1024 + j * 256 + kl + cl * 8),
                LDSP(&Bs[0][0] + i * 8), 16, 0, 0);
        }
        __syncthreads();

        #pragma unroll
        for (int j = 0; j < 4; ++j) {
            short8 bfr[4];
            #pragma unroll
            for (int ni = 0; ni < 4; ++ni) {
                const int row  = wn * 64 + ni * 16 + rlow;
                const int phys = c ^ ((row >> 1) & 3);
                bfr[ni] = *(const short8*)((const char*)Bs[j] + row * 64 + phys * 16);
            }
            #pragma unroll
            for (int mi = 0; mi < 4; ++mi) {
                const int prow = wm * 64 + mi * 16 + rlow + 3 - j;
                const int phys = c ^ ((prow >> 1) & 3);
                const short8 af = *(const short8*)((const char*)As + prow * 64 + phys * 16);
                #pragma unroll
                for (int ni = 0; ni < 4; ++ni)
                    acc[mi][ni] = __builtin_amdgcn_mfma_f32_16x16x32_bf16(
                        af, bfr[ni], acc[mi][ni], 0, 0, 0);
            }
        }
        __syncthreads();
    }

    const int q4 = lane >> 4;
    #pragma unroll
    for (int ni = 0; ni < 4; ++ni) {
        const int col = col0 + wn * 64 + ni * 16 + rlow;
        const float bv = cK4[col];
        #pragma unroll
        for (int mi = 0; mi < 4; ++mi) {
            #pragma unroll
            for (int q = 0; q < 4; ++q) {
                const int row = row0 + wm * 64 + mi * 16 + q4 * 4 + q;
                if ((row & 255) >= 4)
                    yp[(size_t)row * 256 + col] = acc[mi][ni][q] + bv;
            }
        }
    }
}

// ---------------------------------------------------------------------------
// gather hi/lo bf16 B-fragments of a 256x256 fp32 matrix
// ---------------------------------------------------------------------------
static __device__ __forceinline__ void gather_frags(
    const float* __restrict__ M, int col0, int rlow, int kg,
    short8 (&wh)[2][8], short8 (&wl)[2][8])
{
    #pragma unroll
    for (int tile = 0; tile < 2; ++tile) {
        const int col = col0 + tile * 16 + rlow;
        for (int kc = 0; kc < 8; ++kc) {
            const int k0 = kc * 32 + kg * 8;
            short8 h, l;
            for (int i = 0; i < 8; ++i) {
                const float w = M[(size_t)(k0 + i) * 256 + col];
                const unsigned short hb = f2bf(w);
                h[i] = (short)hb;
                l[i] = (short)f2bf(w - bf2f(hb));
            }
            wh[tile][kc] = h;
            wl[tile][kc] = l;
        }
    }
}

// ---------------------------------------------------------------------------
// Unrolled scan (r8/r10 version, measured-good): y_t = y_{t-4}@W4 + D4[t],
// D4 f32 IN-PLACE in yp; D4 prefetched one super-step ahead; LGKM-only
// barriers (global ops stay in flight).
// ---------------------------------------------------------------------------
__global__ __launch_bounds__(512, 1) void scan4(
    const float* __restrict__ WK, const float* __restrict__ W4,
    const float* __restrict__ stash,
    const float* __restrict__ y, float* __restrict__ yp)
{
    __shared__ __align__(16) __hip_bfloat16 cbuf[2][2][16 * 256];

    const int tid  = threadIdx.x;
    const int lane = tid & 63;
    const int wid  = tid >> 6;
    const int b0   = blockIdx.x * 4;
    const int col0 = wid * 32;
    const int rlow = lane & 15;
    const int kg   = lane >> 4;
    const int rswz = (rlow & 7) << 4;

    // init: phase-0 rows = y0
    #pragma unroll
    for (int e = 0; e < 2; ++e) {
        const int idx = tid * 2 + e;
        const int br  = idx >> 8;
        const int cc  = idx & 255;
        const float v = y[(size_t)(b0 + br) * 65536 + cc];
        yp[(size_t)(b0 + br) * 65536 + cc] = v;
        const unsigned short hb = f2bf(v);
        const unsigned short lb = f2bf(v - bf2f(hb));
        const int byte = (br * 512 + cc * 2) ^ ((br & 7) << 4);
        *(unsigned short*)((char*)&cbuf[0][0][0] + byte) = hb;
        *(unsigned short*)((char*)&cbuf[0][1][0] + byte) = lb;
    }
    __syncthreads();

    short8 wh[2][8], wl[2][8];
    gather_frags(WK, col0, rlow, kg, wh, wl);

    // prologue p = 1..3
    for (int p = 1; p < 4; ++p) {
        f32x4 aHH[2], aHL[2], aLH[2];
        #pragma unroll
        for (int tile = 0; tile < 2; ++tile) {
            aHH[tile] = {0.f, 0.f, 0.f, 0.f};
            aHL[tile] = {0.f, 0.f, 0.f, 0.f};
            aLH[tile] = {0.f, 0.f, 0.f, 0.f};
        }
        const char* hbase = (const char*)&cbuf[0][0][0];
        const char* lbase = (const char*)&cbuf[0][1][0];
        #pragma unroll
        for (int kc = 0; kc < 8; ++kc) {
            const int off = (rlow * 512 + kg * 16 + kc * 64) ^ rswz;
            const short8 ah = *(const short8*)(hbase + off);
            const short8 al = *(const short8*)(lbase + off);
            aHH[0] = __builtin_amdgcn_mfma_f32_16x16x32_bf16(ah, wh[0][kc], aHH[0], 0, 0, 0);
            aHH[1] = __builtin_amdgcn_mfma_f32_16x16x32_bf16(ah, wh[1][kc], aHH[1], 0, 0, 0);
            aHL[0] = __builtin_amdgcn_mfma_f32_16x16x32_bf16(ah, wl[0][kc], aHL[0], 0, 0, 0);
            aHL[1] = __builtin_amdgcn_mfma_f32_16x16x32_bf16(ah, wl[1][kc], aHL[1], 0, 0, 0);
            aLH[0] = __builtin_amdgcn_mfma_f32_16x16x32_bf16(al, wh[0][kc], aLH[0], 0, 0, 0);
            aLH[1] = __builtin_amdgcn_mfma_f32_16x16x32_bf16(al, wh[1][kc], aLH[1], 0, 0, 0);
        }
        __builtin_amdgcn_sched_barrier(0);
        asm volatile("s_waitcnt lgkmcnt(0)" ::: "memory");
        __builtin_amdgcn_s_barrier();
        __builtin_amdgcn_sched_barrier(0);

        if (kg == p - 1) {
            #pragma unroll
            for (int tile = 0; tile < 2; ++tile) {
                const int col = col0 + tile * 16 + rlow;
                #pragma unroll
                for (int q = 0; q < 4; ++q) {
                    const float cv = stash[((size_t)(b0 + q) * 3 + (p - 1)) * 256 + col];
                    const float yv = aHH[tile][q] + aHL[tile][q] + aLH[tile][q] + cv;
                    const int wr = p * 4 + q;
                    const unsigned short hb = f2bf(yv);
                    const unsigned short lb = f2bf(yv - bf2f(hb));
                    const int byte = (wr * 512 + col * 2) ^ ((wr & 7) << 4);
                    *(unsigned short*)((char*)&cbuf[0][0][0] + byte) = hb;
                    *(unsigned short*)((char*)&cbuf[0][1][0] + byte) = lb;
                    yp[(size_t)(b0 + q) * 65536 + (size_t)p * 256 + col] = yv;
                }
            }
        }
        __builtin_amdgcn_sched_barrier(0);
        asm volatile("s_waitcnt lgkmcnt(0)" ::: "memory");
        __builtin_amdgcn_s_barrier();
        __builtin_amdgcn_sched_barrier(0);
    }

    gather_frags(W4, col0, rlow, kg, wh, wl);

    // prefetch D4 for s=0
    float dv[2][4];
    #pragma unroll
    for (int tile = 0; tile < 2; ++tile) {
        const int col = col0 + tile * 16 + rlow;
        #pragma unroll
        for (int q = 0; q < 4; ++q)
            dv[tile][q] = yp[(size_t)(b0 + q) * 65536 + (size_t)(4 + kg) * 256 + col];
    }

    int cur = 0;
    for (int s = 0; s < 63; ++s) {
        const int tb = 4 + s * 4;

        float dn[2][4];
        if (s < 62) {
            #pragma unroll
            for (int tile = 0; tile < 2; ++tile) {
                const int col = col0 + tile * 16 + rlow;
                #pragma unroll
                for (int q = 0; q < 4; ++q)
                    dn[tile][q] = yp[(size_t)(b0 + q) * 65536
                                     + (size_t)(tb + 4 + kg) * 256 + col];
            }
        }

        f32x4 aHH[2], aHL[2], aLH[2];
        #pragma unroll
        for (int tile = 0; tile < 2; ++tile) {
            aHH[tile] = {0.f, 0.f, 0.f, 0.f};
            aHL[tile] = {0.f, 0.f, 0.f, 0.f};
            aLH[tile] = {0.f, 0.f, 0.f, 0.f};
        }
        const char* hbase = (const char*)&cbuf[cur][0][0];
        const char* lbase = (const char*)&cbuf[cur][1][0];
        #pragma unroll
        for (int kc = 0; kc < 8; ++kc) {
            const int off = (rlow * 512 + kg * 16 + kc * 64) ^ rswz;
            const short8 ah = *(const short8*)(hbase + off);
            const short8 al = *(const short8*)(lbase + off);
            aHH[0] = __builtin_amdgcn_mfma_f32_16x16x32_bf16(ah, wh[0][kc], aHH[0], 0, 0, 0);
            aHH[1] = __builtin_amdgcn_mfma_f32_16x16x32_bf16(ah, wh[1][kc], aHH[1], 0, 0, 0);
            aHL[0] = __builtin_amdgcn_mfma_f32_16x16x32_bf16(ah, wl[0][kc], aHL[0], 0, 0, 0);
            aHL[1] = __builtin_amdgcn_mfma_f32_16x16x32_bf16(ah, wl[1][kc], aHL[1], 0, 0, 0);
            aLH[0] = __builtin_amdgcn_mfma_f32_16x16x32_bf16(al, wh[0][kc], aLH[0], 0, 0, 0);
            aLH[1] = __builtin_amdgcn_mfma_f32_16x16x32_bf16(al, wh[1][kc], aLH[1], 0, 0, 0);
        }

        char* whb = (char*)&cbuf[cur ^ 1][0][0];
        char* wlb = (char*)&cbuf[cur ^ 1][1][0];
        #pragma unroll
        for (int tile = 0; tile < 2; ++tile) {
            const int col = col0 + tile * 16 + rlow;
            #pragma unroll
            for (int q = 0; q < 4; ++q) {
                const int row = kg * 4 + q;
                const float yv = aHH[tile][q] + aHL[tile][q] + aLH[tile][q] + dv[tile][q];
                const unsigned short hb = f2bf(yv);
                const unsigned short lb = f2bf(yv - bf2f(hb));
                const int byte = (row * 512 + col * 2) ^ ((row & 7) << 4);
                *(unsigned short*)(whb + byte) = hb;
                *(unsigned short*)(wlb + byte) = lb;
                yp[(size_t)(b0 + q) * 65536 + (size_t)(tb + kg) * 256 + col] = yv;
            }
        }
        if (s < 62) {
            #pragma unroll
            for (int tile = 0; tile < 2; ++tile)
                #pragma unroll
                for (int q = 0; q < 4; ++q)
                    dv[tile][q] = dn[tile][q];
        }

        __builtin_amdgcn_sched_barrier(0);
        asm volatile("s_waitcnt lgkmcnt(0)" ::: "memory");
        __builtin_amdgcn_s_barrier();
        __builtin_amdgcn_sched_barrier(0);
        cur ^= 1;
    }
}

// ---------------------------------------------------------------------------
extern "C" void kernel_launch(void* const* d_in, const int* in_sizes, int n_in,
                              void* d_out, int out_size, void* d_ws, size_t ws_size,
                              hipStream_t stream)
{
    const float* x   = (const float*)d_in[0];
    const float* u   = (const float*)d_in[1];
    const float* Wx1 = (const float*)d_in[2];
    const float* bx1 = (const float*)d_in[3];
    const float* Wx2 = (const float*)d_in[4];
    const float* bx2 = (const float*)d_in[5];
    const float* Wx3 = (const float*)d_in[6];
    const float* Wu1 = (const float*)d_in[7];
    const float* bu1 = (const float*)d_in[8];
    const float* Wu2 = (const float*)d_in[9];
    const float* WB  = (const float*)d_in[10];
    const float* WK  = (const float*)d_in[11];
    const float* bK  = (const float*)d_in[12];

    float* y  = (float*)d_out;
    float* yp = y + (size_t)MM * 256;

    char* ws = (char*)d_ws;
    __hip_bfloat16* x_bf = (__hip_bfloat16*)(ws);
    __hip_bfloat16* u_bf = (__hip_bfloat16*)(ws + 16777216);
    __hip_bfloat16* wTb  = (__hip_bfloat16*)(ws + 33554432);
    __hip_bfloat16* Wx1T = wTb;
    __hip_bfloat16* Wx2T = wTb + 16384;
    __hip_bfloat16* Wx3T = wTb + 81920;
    __hip_bfloat16* Wu1T = wTb + 131072;
    __hip_bfloat16* Wu2T = wTb + 147456;
    __hip_bfloat16* WBT  = wTb + 196608;
    __hip_bfloat16* t2   = (__hip_bfloat16*)(ws + 34078720);     // v (M x 192)
    float* W2f   = (float*)(ws + 101187584);
    float* W3f   = (float*)(ws + 101449728);
    float* W4f   = (float*)(ws + 101711872);
    float* WBWf  = (float*)(ws + 101974016);
    float* WBW2f = (float*)(ws + 102236160);
    float* WBW3f = (float*)(ws + 102498304);
    __hip_bfloat16* WBT4 = (__hip_bfloat16*)(ws + 102760448);
    float* cK4   = (float*)(ws + 103284736);
    float* stash = (float*)(ws + 103285760);

    dim3 blk(256);

    // fused conversions + weight transposes
    prep0<<<17408, blk, 0, stream>>>(x, u, x_bf, u_bf, y,
                                     Wx1, Wx2, Wx3, Wu1, Wu2, WB,
                                     Wx1T, Wx2T, Wx3T, Wu1T, Wu2T, WBT);

    // W-power products: 2 batched levels instead of 6 serial GEMMs
    {
        G5 L1 = {{WK, WB, nullptr, nullptr, nullptr},
                 {WK, WK, nullptr, nullptr, nullptr},
                 {W2f, WBWf, nullptr, nullptr, nullptr}};
        wgemm<<<32, blk, 0, stream>>>(L1);
        G5 L2 = {{W2f, W2f, WBWf, WBWf, nullptr},
                 {WK, W2f, WK, W2f, nullptr},
                 {W3f, W4f, WBW2f, WBW3f, nullptr}};
        wgemm<<<64, blk, 0, stream>>>(L2);
    }
    bigbt_ck<<<1025, blk, 0, stream>>>(WB, WBWf, WBW2f, WBW3f, WBT4,
                                       bK, WK, W2f, W3f, cK4);

    // fused feedforward chains
    ffx<<<1024, dim3(512), 0, stream>>>(x_bf, Wx1T, bx1, Wx2T, bx2, Wx3T, y);
    ffu<<<1024, dim3(512), 0, stream>>>(u_bf, Wu1T, bu1, Wu2T, t2);

    // prologue constants + single-pass D4 (f32, in-place in yp, t>=4)
    stashk<<<512, blk, 0, stream>>>(u_bf, t2, WBT, bK, stash);
    d4g<<<dim3(1024, 2), blk, 0, stream>>>(u_bf, t2, WBT4, cK4, yp);

    // unrolled recurrence
    scan4<<<128, dim3(512), 0, stream>>>(WK, W4f, stash, y, yp);
}